// Round 2
// baseline (270.120 us; speedup 1.0000x reference)
//
#include <hip/hip_runtime.h>
#include <cstdint>

typedef __attribute__((ext_vector_type(4))) int int32x4;

#define GLOBAL_AS __attribute__((address_space(1)))
#define LDS_AS    __attribute__((address_space(3)))

// ---------------------------------------------------------------------------
// Kernel 0: pack int32-carried weight [N*K] (values in [-128,127]) to int8.
// Harness pushes integer inputs as int32; truncate low bytes, vectorized.
// ---------------------------------------------------------------------------
__global__ __launch_bounds__(256) void pack_w(
    const int* __restrict__ w32, uint32_t* __restrict__ w8_as_u32)
{
    const size_t i = (size_t)blockIdx.x * 256 + threadIdx.x; // 4 elems each
    const int4 v = ((const int4*)w32)[i];
    w8_as_u32[i] = (v.x & 0xff) | ((v.y & 0xff) << 8) |
                   ((v.z & 0xff) << 16) | ((uint32_t)(v.w & 0xff) << 24);
}

// ---------------------------------------------------------------------------
// Kernel 1: per-row dynamic symmetric int8 quantization.
// One block (256 threads) per row of [M, K] fp32, K=4096.
// ---------------------------------------------------------------------------
__global__ __launch_bounds__(256) void quant_rows(
    const float* __restrict__ in, int8_t* __restrict__ q,
    float* __restrict__ sa, int K)
{
    const int row = blockIdx.x;
    const float4* rp = (const float4*)(in + (size_t)row * K);
    const int t = threadIdx.x;

    float amax = 0.f;
    float4 v[4]; // K/4/256 == 4 float4 per thread for K=4096
#pragma unroll
    for (int i = 0; i < 4; ++i) {
        v[i] = rp[t + (i << 8)];
        amax = fmaxf(amax,
               fmaxf(fmaxf(fabsf(v[i].x), fabsf(v[i].y)),
                     fmaxf(fabsf(v[i].z), fabsf(v[i].w))));
    }

#pragma unroll
    for (int off = 32; off; off >>= 1)
        amax = fmaxf(amax, __shfl_xor(amax, off));
    __shared__ float smax[4];
    if ((t & 63) == 0) smax[t >> 6] = amax;
    __syncthreads();
    amax = fmaxf(fmaxf(smax[0], smax[1]), fmaxf(smax[2], smax[3]));

    const float scale = (amax > 0.f) ? (amax / 127.f) : 1.f;
    if (t == 0) sa[row] = scale;
    const float rs = 1.f / scale;

    int* qrow = (int*)(q + (size_t)row * K);
#pragma unroll
    for (int i = 0; i < 4; ++i) {
        int a = __float2int_rn(v[i].x * rs);
        int b = __float2int_rn(v[i].y * rs);
        int c = __float2int_rn(v[i].z * rs);
        int d = __float2int_rn(v[i].w * rs);
        a = max(-128, min(127, a));
        b = max(-128, min(127, b));
        c = max(-128, min(127, c));
        d = max(-128, min(127, d));
        qrow[t + (i << 8)] = (a & 0xff) | ((b & 0xff) << 8) |
                             ((c & 0xff) << 16) | ((d & 0xff) << 24);
    }
}

// ---------------------------------------------------------------------------
// Kernel 2: int8 GEMM  C[m][n] = sum_k q[m][k] * W[n][k], dequant epilogue.
// m97 structure: 128x128 tile, BK=64, 4 waves (2x2), each wave 64x64 output,
// mfma_i32_16x16x64_i8 (full BK per MFMA), global_load_lds width=16,
// 2-barrier single-buffered LDS.
// ---------------------------------------------------------------------------
__device__ __forceinline__ void async_load16(const int8_t* g, int8_t* lds) {
    __builtin_amdgcn_global_load_lds((const GLOBAL_AS char*)g,
                                     (LDS_AS char*)lds, 16, 0, 0);
}

__global__ __launch_bounds__(256) void w8a8_gemm(
    const int8_t* __restrict__ Aq, const int8_t* __restrict__ W,
    const float* __restrict__ sa, const float* __restrict__ wsc,
    const float* __restrict__ bias, float* __restrict__ out,
    int M, int N, int K)
{
    __shared__ int8_t lA[128 * 64];
    __shared__ int8_t lB[128 * 64];

    const int NB = N >> 7; // N / 128
    const int nwg = gridDim.x;
    // XCD-aware swizzle (bijective: nwg % 8 == 0 for these shapes)
    const int cpx = nwg >> 3;
    const int wg = (blockIdx.x & 7) * cpx + (blockIdx.x >> 3);
    const int bm = wg / NB, bn = wg % NB;

    const int t = threadIdx.x;
    const int w = t >> 6, l = t & 63;
    const int wr = w >> 1, wc = w & 1;
    const int r = l & 15, q4 = l >> 4;

    // staging: 512 chunks of 16B per 8KB tile; thread t handles chunks t, t+256
    const size_t rowA = (size_t)bm * 128;
    const size_t rowB = (size_t)bn * 128;
    const int c0 = t;
    const int colb = (c0 & 3) << 4; // byte col within BK=64
    const int8_t* gA0 = Aq + (rowA + (c0 >> 2)) * (size_t)K + colb;
    const int8_t* gA1 = Aq + (rowA + (c0 >> 2) + 64) * (size_t)K + colb;
    const int8_t* gB0 = W  + (rowB + (c0 >> 2)) * (size_t)K + colb;
    const int8_t* gB1 = W  + (rowB + (c0 >> 2) + 64) * (size_t)K + colb;
    int8_t* lA0 = &lA[c0 * 16];
    int8_t* lA1 = &lA[(c0 + 256) * 16];
    int8_t* lB0 = &lB[c0 * 16];
    int8_t* lB1 = &lB[(c0 + 256) * 16];

    int32x4 acc[4][4];
#pragma unroll
    for (int m = 0; m < 4; ++m)
#pragma unroll
        for (int n = 0; n < 4; ++n)
            acc[m][n] = (int32x4){0, 0, 0, 0};

    for (int kt = 0; kt < K; kt += 64) {
        __syncthreads(); // all waves done reading previous tile
        async_load16(gA0 + kt, lA0);
        async_load16(gA1 + kt, lA1);
        async_load16(gB0 + kt, lB0);
        async_load16(gB1 + kt, lB1);
        __syncthreads(); // compiler drains vmcnt before s_barrier

        int32x4 af[4], bf[4];
#pragma unroll
        for (int m = 0; m < 4; ++m)
            af[m] = *(const int32x4*)&lA[((wr << 6) + (m << 4) + r) * 64 + (q4 << 4)];
#pragma unroll
        for (int n = 0; n < 4; ++n)
            bf[n] = *(const int32x4*)&lB[((wc << 6) + (n << 4) + r) * 64 + (q4 << 4)];

#pragma unroll
        for (int m = 0; m < 4; ++m)
#pragma unroll
            for (int n = 0; n < 4; ++n)
                acc[m][n] = __builtin_amdgcn_mfma_i32_16x16x64_i8(
                    af[m], bf[n], acc[m][n], 0, 0, 0);
    }

    // epilogue: out[row][col] = acc * sa[row] * wsc[col] + bias[col]
    // C/D mapping (16x16 shape): col = lane&15, row = (lane>>4)*4 + j
    const int row0 = bm * 128 + (wr << 6) + (q4 << 2); // + m*16 + j
    const int col0 = bn * 128 + (wc << 6) + r;         // + n*16

    float sarow[4][4];
#pragma unroll
    for (int m = 0; m < 4; ++m)
#pragma unroll
        for (int j = 0; j < 4; ++j)
            sarow[m][j] = sa[row0 + (m << 4) + j];

#pragma unroll
    for (int n = 0; n < 4; ++n) {
        const int col = col0 + (n << 4);
        const float wn = wsc[col];
        const float bn_ = bias[col];
#pragma unroll
        for (int m = 0; m < 4; ++m) {
            const int rowb = row0 + (m << 4);
#pragma unroll
            for (int j = 0; j < 4; ++j) {
                out[(size_t)(rowb + j) * N + col] =
                    (float)acc[m][n][j] * sarow[m][j] * wn + bn_;
            }
        }
    }
}

// ---------------------------------------------------------------------------
extern "C" void kernel_launch(void* const* d_in, const int* in_sizes, int n_in,
                              void* d_out, int out_size, void* d_ws, size_t ws_size,
                              hipStream_t stream) {
    const float* inp  = (const float*)d_in[0];
    const int*   w32  = (const int*)d_in[1];   // int8 values carried as int32
    const float* wsc  = (const float*)d_in[2];
    const float* bias = (const float*)d_in[3];
    float* out = (float*)d_out;

    const int N = in_sizes[2];            // 4096
    const int K = in_sizes[1] / N;        // 4096
    const int M = in_sizes[0] / K;        // 8192

    // workspace layout: q[M*K] int8 | sa[M] f32 | W8[N*K] int8
    int8_t* q  = (int8_t*)d_ws;
    float*  sa = (float*)((char*)d_ws + (size_t)M * K);
    int8_t* w8 = (int8_t*)((char*)d_ws + (size_t)M * K + (size_t)M * 4 + 256);

    const size_t nw4 = ((size_t)N * K) / 4; // int32x4 packs
    pack_w<<<(int)(nw4 / 256), 256, 0, stream>>>(w32, (uint32_t*)w8);

    quant_rows<<<M, 256, 0, stream>>>(inp, q, sa, K);

    const int nwg = (M / 128) * (N / 128); // 2048
    w8a8_gemm<<<nwg, 256, 0, stream>>>(q, w8, sa, wsc, bias, out, M, N, K);
}

// Round 3
// 211.146 us; speedup vs baseline: 1.2793x; 1.2793x over previous
//
#include <hip/hip_runtime.h>
#include <cstdint>

typedef __attribute__((ext_vector_type(4))) int int32x4;

#define GLOBAL_AS __attribute__((address_space(1)))
#define LDS_AS    __attribute__((address_space(3)))

// ---------------------------------------------------------------------------
// Kernel 0: pack int32-carried weight [N*K] (values in [-128,127]) to int8.
// ---------------------------------------------------------------------------
__global__ __launch_bounds__(256) void pack_w(
    const int* __restrict__ w32, uint32_t* __restrict__ w8_as_u32)
{
    const size_t i = (size_t)blockIdx.x * 256 + threadIdx.x; // 4 elems each
    const int4 v = ((const int4*)w32)[i];
    w8_as_u32[i] = (v.x & 0xff) | ((v.y & 0xff) << 8) |
                   ((v.z & 0xff) << 16) | ((uint32_t)(v.w & 0xff) << 24);
}

// ---------------------------------------------------------------------------
// Kernel 1: per-row dynamic symmetric int8 quantization (K=4096).
// ---------------------------------------------------------------------------
__global__ __launch_bounds__(256) void quant_rows(
    const float* __restrict__ in, int8_t* __restrict__ q,
    float* __restrict__ sa, int K)
{
    const int row = blockIdx.x;
    const float4* rp = (const float4*)(in + (size_t)row * K);
    const int t = threadIdx.x;

    float amax = 0.f;
    float4 v[4];
#pragma unroll
    for (int i = 0; i < 4; ++i) {
        v[i] = rp[t + (i << 8)];
        amax = fmaxf(amax,
               fmaxf(fmaxf(fabsf(v[i].x), fabsf(v[i].y)),
                     fmaxf(fabsf(v[i].z), fabsf(v[i].w))));
    }

#pragma unroll
    for (int off = 32; off; off >>= 1)
        amax = fmaxf(amax, __shfl_xor(amax, off));
    __shared__ float smax[4];
    if ((t & 63) == 0) smax[t >> 6] = amax;
    __syncthreads();
    amax = fmaxf(fmaxf(smax[0], smax[1]), fmaxf(smax[2], smax[3]));

    const float scale = (amax > 0.f) ? (amax / 127.f) : 1.f;
    if (t == 0) sa[row] = scale;
    const float rs = 1.f / scale;

    int* qrow = (int*)(q + (size_t)row * K);
#pragma unroll
    for (int i = 0; i < 4; ++i) {
        int a = __float2int_rn(v[i].x * rs);
        int b = __float2int_rn(v[i].y * rs);
        int c = __float2int_rn(v[i].z * rs);
        int d = __float2int_rn(v[i].w * rs);
        a = max(-128, min(127, a));
        b = max(-128, min(127, b));
        c = max(-128, min(127, c));
        d = max(-128, min(127, d));
        qrow[t + (i << 8)] = (a & 0xff) | ((b & 0xff) << 8) |
                             ((c & 0xff) << 16) | ((d & 0xff) << 24);
    }
}

// ---------------------------------------------------------------------------
// Kernel 2: int8 GEMM, 256x256 tile, 8-phase schedule (T1+T2+T3+T4+T5).
//
// Geometry: BM=BN=256, BK=64 (one mfma_i32_16x16x64_i8 spans the K-tile).
// 512 threads = 8 waves (2 M x 4 N); per-wave output 128x64 = 8x4 frags.
// LDS: ring of 4 K-tile buffers, each {A 256x64 | B 256x64} = 32 KiB -> 128 KiB.
//
// Staging ledger (chunk = 128 rows x 64 B = 8 KiB = 1 gload_lds/thread):
//   prologue: stage K-tiles 0,1 (8 chunks); vmcnt(4) -> tile0 landed; barrier.
//   group g (4 phases, computes K-tile g from ring g%4):
//     phase q: 6x ds_read_b128 (quadrant frags) | stage chunk q of K-tile g+2
//              into ring (g+2)%4 | barrier | setprio(1) 8x MFMA setprio(0) |
//              [q==3: vmcnt(4) -> K-tile g+1 landed, g+2's 4 chunks in flight]
//              | barrier.
//   WAR safe: ring slot (g+2)%4 last read at group g-2 (barrier-separated).
//   Tail: groups NT-2, NT-1 stage nothing; vmcnt(0) at NT-2 boundary.
//
// T2 swizzle: 16B slot s at row r holds global slot s ^ ((r>>1)&3); applied on
// the gload_lds GLOBAL source (LDS dest stays linear, rule #21) and on the
// ds_read address. Per-16-lane bank-granule map (4r + (q4^xr)) mod 8 is a
// perfect 8-spread -> 2-way (free).
// ---------------------------------------------------------------------------
__device__ __forceinline__ void async_load16(const int8_t* g, int8_t* lds) {
    __builtin_amdgcn_global_load_lds((const GLOBAL_AS char*)g,
                                     (LDS_AS char*)lds, 16, 0, 0);
}

__global__ __launch_bounds__(512, 2) void w8a8_gemm(
    const int8_t* __restrict__ Aq, const int8_t* __restrict__ W,
    const float* __restrict__ sa, const float* __restrict__ wsc,
    const float* __restrict__ bias, float* __restrict__ out,
    int M, int N, int K)
{
    __shared__ int8_t lds[4 * 32768]; // 128 KiB

    const int NB = N >> 8; // N/256
    const int nwg = gridDim.x;
    // XCD-aware swizzle (nwg % 8 == 0 -> bijective)
    const int cpx = nwg >> 3;
    const int wg = (blockIdx.x & 7) * cpx + (blockIdx.x >> 3);
    const int bm = wg / NB, bn = wg % NB;

    const int t = threadIdx.x;
    const int lane = t & 63, wid = t >> 6;
    const int wr = wid >> 2, wc = wid & 3;
    const int r = lane & 15, q4 = lane >> 4;

    // ---- staging (per-thread): chunk-local row t>>2, swizzled 16B col ----
    const int srow = t >> 2;                            // 0..127
    const int scol = (((t & 3) ^ ((t >> 3) & 3)) << 4); // source col, swizzled
    const int8_t* gA = Aq + ((size_t)bm * 256 + srow) * (size_t)K + scol;
    const int8_t* gB = W  + ((size_t)bn * 256 + srow) * (size_t)K + scol;
    const size_t half_stride = (size_t)128 * K;
    int8_t* ldsw = &lds[t * 16];

    auto stage = [&](int ring, int kbyte, int c) {
        const int8_t* src = (c < 2 ? gA : gB) + (size_t)(c & 1) * half_stride + kbyte;
        async_load16(src, ldsw + ring * 32768 + (c >> 1) * 16384 + (c & 1) * 8192);
    };

    // ---- fragment read bases (swizzled) ----
    // (row>>1)&3 reduces to (r>>1)&3 since all row offsets are mult of 8
    const int xr = (r >> 1) & 3;
    const int ca = (q4 ^ xr) << 4;
    const int aoff0 = (wr * 128 + r) * 64 + ca;        // + m*1024 + ring*32768
    const int boff0 = 16384 + (wc * 64 + r) * 64 + ca; // + n*1024 + ring*32768

    int32x4 acc[8][4];
#pragma unroll
    for (int m = 0; m < 8; ++m)
#pragma unroll
        for (int n = 0; n < 4; ++n)
            acc[m][n] = (int32x4){0, 0, 0, 0};

    const int NT = K >> 6; // 64 K-tiles

    // prologue: stage K-tiles 0 (ring 0) and 1 (ring 1)
#pragma unroll
    for (int c = 0; c < 4; ++c) stage(0, 0, c);
#pragma unroll
    for (int c = 0; c < 4; ++c) stage(1, 64, c);
    asm volatile("s_waitcnt vmcnt(4)" ::: "memory");
    asm volatile("s_barrier" ::: "memory");

    for (int g = 0; g < NT; ++g) {
        const int rbase = (g & 3) * 32768;
        const int sring = (g + 2) & 3;
        const int skb = (g + 2) << 6;
        const bool do_stage = (g + 2) < NT;
#pragma unroll
        for (int q = 0; q < 4; ++q) {
            const int qm = (q >> 1) * 4; // m-frag quadrant base
            const int qn = (q & 1) * 2;  // n-frag quadrant base

            int32x4 af[4], bf[2];
#pragma unroll
            for (int i = 0; i < 4; ++i)
                af[i] = *(const int32x4*)&lds[rbase + aoff0 + (qm + i) * 1024];
#pragma unroll
            for (int j = 0; j < 2; ++j)
                bf[j] = *(const int32x4*)&lds[rbase + boff0 + (qn + j) * 1024];

            if (do_stage) stage(sring, skb, q);

            asm volatile("s_barrier" ::: "memory");
            __builtin_amdgcn_s_setprio(1);
#pragma unroll
            for (int i = 0; i < 4; ++i)
#pragma unroll
                for (int j = 0; j < 2; ++j)
                    acc[qm + i][qn + j] = __builtin_amdgcn_mfma_i32_16x16x64_i8(
                        af[i], bf[j], acc[qm + i][qn + j], 0, 0, 0);
            __builtin_amdgcn_s_setprio(0);

            if (q == 3) {
                if (g < NT - 2)
                    asm volatile("s_waitcnt vmcnt(4)" ::: "memory");
                else
                    asm volatile("s_waitcnt vmcnt(0)" ::: "memory");
            }
            asm volatile("s_barrier" ::: "memory");
        }
    }

    // ---- epilogue: C/D map col=lane&15, row=(lane>>4)*4+j ----
    const int row0 = bm * 256 + wr * 128 + (q4 << 2); // + m*16 + j
    const int col0 = bn * 256 + wc * 64 + r;          // + n*16

    float sarow[8][4];
#pragma unroll
    for (int m = 0; m < 8; ++m)
#pragma unroll
        for (int j = 0; j < 4; ++j)
            sarow[m][j] = sa[row0 + (m << 4) + j];

#pragma unroll
    for (int n = 0; n < 4; ++n) {
        const int col = col0 + (n << 4);
        const float wn = wsc[col];
        const float bn_ = bias[col];
#pragma unroll
        for (int m = 0; m < 8; ++m) {
            const int rowb = row0 + (m << 4);
#pragma unroll
            for (int j = 0; j < 4; ++j) {
                out[(size_t)(rowb + j) * N + col] =
                    (float)acc[m][n][j] * sarow[m][j] * wn + bn_;
            }
        }
    }
}

// ---------------------------------------------------------------------------
extern "C" void kernel_launch(void* const* d_in, const int* in_sizes, int n_in,
                              void* d_out, int out_size, void* d_ws, size_t ws_size,
                              hipStream_t stream) {
    const float* inp  = (const float*)d_in[0];
    const int*   w32  = (const int*)d_in[1];   // int8 values carried as int32
    const float* wsc  = (const float*)d_in[2];
    const float* bias = (const float*)d_in[3];
    float* out = (float*)d_out;

    const int N = in_sizes[2];            // 4096
    const int K = in_sizes[1] / N;        // 4096
    const int M = in_sizes[0] / K;        // 8192

    // workspace: q[M*K] i8 | sa[M] f32 | W8[N*K] i8
    int8_t* q  = (int8_t*)d_ws;
    float*  sa = (float*)((char*)d_ws + (size_t)M * K);
    int8_t* w8 = (int8_t*)((char*)d_ws + (size_t)M * K + (size_t)M * 4 + 256);

    const size_t nw4 = ((size_t)N * K) / 4;
    pack_w<<<(int)(nw4 / 256), 256, 0, stream>>>(w32, (uint32_t*)w8);

    quant_rows<<<M, 256, 0, stream>>>(inp, q, sa, K);

    const int nwg = (M / 256) * (N / 256); // 512
    w8a8_gemm<<<nwg, 512, 0, stream>>>(q, w8, sa, wsc, bias, out, M, N, K);
}

// Round 4
// 200.163 us; speedup vs baseline: 1.3495x; 1.0549x over previous
//
#include <hip/hip_runtime.h>
#include <cstdint>

typedef __attribute__((ext_vector_type(4))) int int32x4;
typedef __attribute__((ext_vector_type(16))) int int32x16;

#define GLOBAL_AS __attribute__((address_space(1)))
#define LDS_AS    __attribute__((address_space(3)))

// ---------------------------------------------------------------------------
// Kernel 0: pack int32-carried weight [N*K] (values in [-128,127]) to int8.
// ---------------------------------------------------------------------------
__global__ __launch_bounds__(256) void pack_w(
    const int* __restrict__ w32, uint32_t* __restrict__ w8_as_u32)
{
    const size_t i = (size_t)blockIdx.x * 256 + threadIdx.x; // 4 elems each
    const int4 v = ((const int4*)w32)[i];
    w8_as_u32[i] = (v.x & 0xff) | ((v.y & 0xff) << 8) |
                   ((v.z & 0xff) << 16) | ((uint32_t)(v.w & 0xff) << 24);
}

// ---------------------------------------------------------------------------
// Kernel 1: per-row dynamic symmetric int8 quantization (K=4096).
// ---------------------------------------------------------------------------
__global__ __launch_bounds__(256) void quant_rows(
    const float* __restrict__ in, int8_t* __restrict__ q,
    float* __restrict__ sa, int K)
{
    const int row = blockIdx.x;
    const float4* rp = (const float4*)(in + (size_t)row * K);
    const int t = threadIdx.x;

    float amax = 0.f;
    float4 v[4];
#pragma unroll
    for (int i = 0; i < 4; ++i) {
        v[i] = rp[t + (i << 8)];
        amax = fmaxf(amax,
               fmaxf(fmaxf(fabsf(v[i].x), fabsf(v[i].y)),
                     fmaxf(fabsf(v[i].z), fabsf(v[i].w))));
    }

#pragma unroll
    for (int off = 32; off; off >>= 1)
        amax = fmaxf(amax, __shfl_xor(amax, off));
    __shared__ float smax[4];
    if ((t & 63) == 0) smax[t >> 6] = amax;
    __syncthreads();
    amax = fmaxf(fmaxf(smax[0], smax[1]), fmaxf(smax[2], smax[3]));

    const float scale = (amax > 0.f) ? (amax / 127.f) : 1.f;
    if (t == 0) sa[row] = scale;
    const float rs = 1.f / scale;

    int* qrow = (int*)(q + (size_t)row * K);
#pragma unroll
    for (int i = 0; i < 4; ++i) {
        int a = __float2int_rn(v[i].x * rs);
        int b = __float2int_rn(v[i].y * rs);
        int c = __float2int_rn(v[i].z * rs);
        int d = __float2int_rn(v[i].w * rs);
        a = max(-128, min(127, a));
        b = max(-128, min(127, b));
        c = max(-128, min(127, c));
        d = max(-128, min(127, d));
        qrow[t + (i << 8)] = (a & 0xff) | ((b & 0xff) << 8) |
                             ((c & 0xff) << 16) | ((d & 0xff) << 24);
    }
}

// ---------------------------------------------------------------------------
// Kernel 2: int8 GEMM, 256x256 tile, mfma_i32_32x32x32_i8 (2x ops/LDS-byte),
// 2 phases per K-tile, ring-4 LDS, stage-2-ahead, counted vmcnt(4).
//
// Geometry: BM=BN=256, BK=64. 512 threads = 8 waves (2M x 4N); per-wave
// output 128x64 = 4x2 frags of 32x32. LDS ring of 4 K-tile buffers
// {A 256x64 | B 256x64} = 32 KiB each -> 128 KiB.
//
// Per phase kk in {0,1}: 4 A-frag + 2 B-frag ds_read_b128, stage 2 of the
// 4 chunks of K-tile g+2 into ring (g+2)%4, barrier, setprio(1), 8 MFMA
// (4m x 2n, K=32 slice kk), setprio(0), [kk==1: vmcnt(4)], barrier.
// Ledger: at end of group g, vmcnt(4) -> only K-tile g+2's 4 chunks remain
// in flight; K-tile g+1 fully landed; barrier broadcasts to all waves.
// WAR: ring slot (g+2)%4 last read at group g-2, many barriers apart.
//
// T2 swizzle: LDS 16B-slot s of row r holds global slot s ^ ((r>>1)&3),
// applied on the gload_lds GLOBAL source (LDS dest linear, rule #21) and on
// the ds_read address. Per-16-lane granule map (4r + s^((r>>1)&3)) mod 8 is
// a perfect 8-spread (verified: 0 conflicts in R3).
//
// Fragment maps (32x32 i8): A row = lane&31, k = (lane>>5)*16 + byte;
// B col = lane&31, same k. C/D: col = lane&31,
// row = (reg&3) + 8*(reg>>2) + 4*(lane>>5)  [guide-verified, dtype-indep].
// ---------------------------------------------------------------------------
__device__ __forceinline__ void async_load16(const int8_t* g, int8_t* lds) {
    __builtin_amdgcn_global_load_lds((const GLOBAL_AS char*)g,
                                     (LDS_AS char*)lds, 16, 0, 0);
}

__global__ __launch_bounds__(512, 2) void w8a8_gemm(
    const int8_t* __restrict__ Aq, const int8_t* __restrict__ W,
    const float* __restrict__ sa, const float* __restrict__ wsc,
    const float* __restrict__ bias, float* __restrict__ out,
    int M, int N, int K)
{
    __shared__ int8_t lds[4 * 32768]; // 128 KiB

    const int NB = N >> 8; // N/256
    const int nwg = gridDim.x;
    // XCD-aware swizzle (nwg % 8 == 0 -> bijective)
    const int cpx = nwg >> 3;
    const int wg = (blockIdx.x & 7) * cpx + (blockIdx.x >> 3);
    const int bm = wg / NB, bn = wg % NB;

    const int t = threadIdx.x;
    const int lane = t & 63, wid = t >> 6;
    const int wr = wid >> 2, wc = wid & 3;
    const int l31 = lane & 31, h = lane >> 5;
    const int xr = (lane >> 1) & 3; // == (row>>1)&3 for row = base+l31, base%32==0

    // ---- staging: thread t -> chunk-row t>>2 (0..127), swizzled 16B col ----
    const int srow = t >> 2;
    const int scol = (((t & 3) ^ ((t >> 3) & 3)) << 4);
    const int8_t* gA = Aq + ((size_t)bm * 256 + srow) * (size_t)K + scol;
    const int8_t* gB = W  + ((size_t)bn * 256 + srow) * (size_t)K + scol;
    const size_t half_stride = (size_t)128 * K;
    int8_t* ldsw = &lds[t * 16];

    auto stage = [&](int ring, int kbyte, int c) {
        const int8_t* src = (c < 2 ? gA : gB) + (size_t)(c & 1) * half_stride + kbyte;
        async_load16(src, ldsw + ring * 32768 + (c >> 1) * 16384 + (c & 1) * 8192);
    };

    // ---- fragment read bases (swizzled): global slot for kk,h = 2*kk + h ----
    const int arow = (wr * 128 + l31) * 64;         // + m*2048 + cs + ring
    const int brow = 16384 + (wc * 64 + l31) * 64;  // + n*2048 + cs + ring
    const int cs0 = ((0 + h) ^ xr) << 4;            // kk = 0
    const int cs1 = ((2 + h) ^ xr) << 4;            // kk = 1

    int32x16 acc[4][2];
#pragma unroll
    for (int m = 0; m < 4; ++m)
#pragma unroll
        for (int n = 0; n < 2; ++n)
#pragma unroll
            for (int rgi = 0; rgi < 16; ++rgi)
                acc[m][n][rgi] = 0;

    const int NT = K >> 6; // 64 K-tiles

    // prologue: stage K-tiles 0 (ring 0) and 1 (ring 1)
#pragma unroll
    for (int c = 0; c < 4; ++c) stage(0, 0, c);
#pragma unroll
    for (int c = 0; c < 4; ++c) stage(1, 64, c);
    asm volatile("s_waitcnt vmcnt(4)" ::: "memory");
    asm volatile("s_barrier" ::: "memory");

    for (int g = 0; g < NT; ++g) {
        const int rbase = (g & 3) * 32768;
        const int sring = (g + 2) & 3;
        const int skb = (g + 2) << 6;
        const bool do_stage = (g + 2) < NT;
#pragma unroll
        for (int kk = 0; kk < 2; ++kk) {
            const int cs = kk ? cs1 : cs0;

            int32x4 af[4], bf[2];
#pragma unroll
            for (int m = 0; m < 4; ++m)
                af[m] = *(const int32x4*)&lds[rbase + arow + m * 2048 + cs];
#pragma unroll
            for (int n = 0; n < 2; ++n)
                bf[n] = *(const int32x4*)&lds[rbase + brow + n * 2048 + cs];

            if (do_stage) {
                stage(sring, skb, 2 * kk);
                stage(sring, skb, 2 * kk + 1);
            }

            asm volatile("s_barrier" ::: "memory");
            __builtin_amdgcn_s_setprio(1);
#pragma unroll
            for (int m = 0; m < 4; ++m)
#pragma unroll
                for (int n = 0; n < 2; ++n)
                    acc[m][n] = __builtin_amdgcn_mfma_i32_32x32x32_i8(
                        af[m], bf[n], acc[m][n], 0, 0, 0);
            __builtin_amdgcn_s_setprio(0);

            if (kk == 1) {
                if (g < NT - 2)
                    asm volatile("s_waitcnt vmcnt(4)" ::: "memory");
                else
                    asm volatile("s_waitcnt vmcnt(0)" ::: "memory");
            }
            asm volatile("s_barrier" ::: "memory");
        }
    }

    // ---- epilogue: C/D col = lane&31, row = (reg&3)+8*(reg>>2)+4*h ----
    const int col0 = bn * 256 + wc * 64 + l31;       // + n*32
    const int row00 = bm * 256 + wr * 128 + 4 * h;   // + m*32 + (reg&3)+8*(reg>>2)

#pragma unroll
    for (int m = 0; m < 4; ++m) {
        float sv[16];
#pragma unroll
        for (int rgi = 0; rgi < 16; ++rgi)
            sv[rgi] = sa[row00 + m * 32 + (rgi & 3) + 8 * (rgi >> 2)];
#pragma unroll
        for (int n = 0; n < 2; ++n) {
            const int col = col0 + n * 32;
            const float wn = wsc[col];
            const float bb = bias[col];
#pragma unroll
            for (int rgi = 0; rgi < 16; ++rgi) {
                const int row = row00 + m * 32 + (rgi & 3) + 8 * (rgi >> 2);
                out[(size_t)row * N + col] =
                    (float)acc[m][n][rgi] * sv[rgi] * wn + bb;
            }
        }
    }
}

// ---------------------------------------------------------------------------
extern "C" void kernel_launch(void* const* d_in, const int* in_sizes, int n_in,
                              void* d_out, int out_size, void* d_ws, size_t ws_size,
                              hipStream_t stream) {
    const float* inp  = (const float*)d_in[0];
    const int*   w32  = (const int*)d_in[1];   // int8 values carried as int32
    const float* wsc  = (const float*)d_in[2];
    const float* bias = (const float*)d_in[3];
    float* out = (float*)d_out;

    const int N = in_sizes[2];            // 4096
    const int K = in_sizes[1] / N;        // 4096
    const int M = in_sizes[0] / K;        // 8192

    // workspace: q[M*K] i8 | sa[M] f32 | W8[N*K] i8
    int8_t* q  = (int8_t*)d_ws;
    float*  sa = (float*)((char*)d_ws + (size_t)M * K);
    int8_t* w8 = (int8_t*)((char*)d_ws + (size_t)M * K + (size_t)M * 4 + 256);

    const size_t nw4 = ((size_t)N * K) / 4;
    pack_w<<<(int)(nw4 / 256), 256, 0, stream>>>(w32, (uint32_t*)w8);

    quant_rows<<<M, 256, 0, stream>>>(inp, q, sa, K);

    const int nwg = (M / 256) * (N / 256); // 512
    w8a8_gemm<<<nwg, 512, 0, stream>>>(q, w8, sa, wsc, bias, out, M, N, K);
}

// Round 5
// 199.800 us; speedup vs baseline: 1.3520x; 1.0018x over previous
//
#include <hip/hip_runtime.h>
#include <cstdint>

typedef __attribute__((ext_vector_type(4))) int int32x4;
typedef __attribute__((ext_vector_type(16))) int int32x16;

#define GLOBAL_AS __attribute__((address_space(1)))
#define LDS_AS    __attribute__((address_space(3)))

// ---------------------------------------------------------------------------
// Kernel 0: pack int32-carried weight [N*K] (values in [-128,127]) to int8.
// ---------------------------------------------------------------------------
__global__ __launch_bounds__(256) void pack_w(
    const int* __restrict__ w32, uint32_t* __restrict__ w8_as_u32)
{
    const size_t i = (size_t)blockIdx.x * 256 + threadIdx.x; // 4 elems each
    const int4 v = ((const int4*)w32)[i];
    w8_as_u32[i] = (v.x & 0xff) | ((v.y & 0xff) << 8) |
                   ((v.z & 0xff) << 16) | ((uint32_t)(v.w & 0xff) << 24);
}

// ---------------------------------------------------------------------------
// Kernel 1: per-row dynamic symmetric int8 quantization (K=4096).
// ---------------------------------------------------------------------------
__global__ __launch_bounds__(256) void quant_rows(
    const float* __restrict__ in, int8_t* __restrict__ q,
    float* __restrict__ sa, int K)
{
    const int row = blockIdx.x;
    const float4* rp = (const float4*)(in + (size_t)row * K);
    const int t = threadIdx.x;

    float amax = 0.f;
    float4 v[4];
#pragma unroll
    for (int i = 0; i < 4; ++i) {
        v[i] = rp[t + (i << 8)];
        amax = fmaxf(amax,
               fmaxf(fmaxf(fabsf(v[i].x), fabsf(v[i].y)),
                     fmaxf(fabsf(v[i].z), fabsf(v[i].w))));
    }

#pragma unroll
    for (int off = 32; off; off >>= 1)
        amax = fmaxf(amax, __shfl_xor(amax, off));
    __shared__ float smax[4];
    if ((t & 63) == 0) smax[t >> 6] = amax;
    __syncthreads();
    amax = fmaxf(fmaxf(smax[0], smax[1]), fmaxf(smax[2], smax[3]));

    const float scale = (amax > 0.f) ? (amax / 127.f) : 1.f;
    if (t == 0) sa[row] = scale;
    const float rs = 1.f / scale;

    int* qrow = (int*)(q + (size_t)row * K);
#pragma unroll
    for (int i = 0; i < 4; ++i) {
        int a = __float2int_rn(v[i].x * rs);
        int b = __float2int_rn(v[i].y * rs);
        int c = __float2int_rn(v[i].z * rs);
        int d = __float2int_rn(v[i].w * rs);
        a = max(-128, min(127, a));
        b = max(-128, min(127, b));
        c = max(-128, min(127, c));
        d = max(-128, min(127, d));
        qrow[t + (i << 8)] = (a & 0xff) | ((b & 0xff) << 8) |
                             ((c & 0xff) << 16) | ((d & 0xff) << 24);
    }
}

// ---------------------------------------------------------------------------
// Kernel 2: int8 GEMM, 256x256 tile, mfma_i32_32x32x32_i8, 2 phases/K-tile,
// ring-4 LDS, stage-2-ahead, counted vmcnt(4).
//
// T2 swizzle v2 (R5): LDS 16B-slot s of row r holds global slot s ^ P(r),
// P(r) = ((r>>1) ^ (r>>3)) & 3  — period 32 in r.
// Quad model: granule-quad = 4*(r&1) + slot. Stride-8 row groups {r,r+8,
// r+16,r+24} get 4 DISTINCT P values (bit r>>3 varies) -> slots spread over
// all 4 -> 2 lanes/quad (free); contiguous-8 lane groups remain a perfect
// 8-spread. R4's P=(r>>1)&3 (period 8) put 4 same-h lanes on one quad ->
// 4-way -> the measured 1.26e7 conflicts.
// Applied on the gload_lds GLOBAL source (LDS dest linear, rule #21) and on
// the ds_read address (same involution). All row bases (wr*128, wc*64, m*32,
// n*32, +128 chunk half) vanish in P after &3, so P(base+l31) = P(l31).
//
// Fragment maps (32x32 i8): A row = lane&31, k = (lane>>5)*16 + byte;
// B col = lane&31, same k. C/D: col = lane&31,
// row = (reg&3) + 8*(reg>>2) + 4*(lane>>5)  [guide-verified, dtype-indep].
// ---------------------------------------------------------------------------
__device__ __forceinline__ void async_load16(const int8_t* g, int8_t* lds) {
    __builtin_amdgcn_global_load_lds((const GLOBAL_AS char*)g,
                                     (LDS_AS char*)lds, 16, 0, 0);
}

__global__ __launch_bounds__(512, 2) void w8a8_gemm(
    const int8_t* __restrict__ Aq, const int8_t* __restrict__ W,
    const float* __restrict__ sa, const float* __restrict__ wsc,
    const float* __restrict__ bias, float* __restrict__ out,
    int M, int N, int K)
{
    __shared__ int8_t lds[4 * 32768]; // 128 KiB

    const int NB = N >> 8; // N/256
    const int nwg = gridDim.x;
    // XCD-aware swizzle (nwg % 8 == 0 -> bijective)
    const int cpx = nwg >> 3;
    const int wg = (blockIdx.x & 7) * cpx + (blockIdx.x >> 3);
    const int bm = wg / NB, bn = wg % NB;

    const int t = threadIdx.x;
    const int lane = t & 63, wid = t >> 6;
    const int wr = wid >> 2, wc = wid & 3;
    const int l31 = lane & 31, h = lane >> 5;
    // P(l31): lane>>1 adds 16h (&3 -> 0), lane>>3 adds 4h (&3 -> 0) => ok
    const int pswz = ((lane >> 1) ^ (lane >> 3)) & 3;

    // ---- staging: thread t -> chunk-row t>>2 (0..127), swizzled 16B col ----
    // global slot = (t&3) ^ P(t>>2), P(t>>2) = ((t>>3) ^ (t>>5)) & 3
    const int srow = t >> 2;
    const int scol = (((t & 3) ^ ((t >> 3) & 3) ^ ((t >> 5) & 3)) << 4);
    const int8_t* gA = Aq + ((size_t)bm * 256 + srow) * (size_t)K + scol;
    const int8_t* gB = W  + ((size_t)bn * 256 + srow) * (size_t)K + scol;
    const size_t half_stride = (size_t)128 * K;
    int8_t* ldsw = &lds[t * 16];

    auto stage = [&](int ring, int kbyte, int c) {
        const int8_t* src = (c < 2 ? gA : gB) + (size_t)(c & 1) * half_stride + kbyte;
        async_load16(src, ldsw + ring * 32768 + (c >> 1) * 16384 + (c & 1) * 8192);
    };

    // ---- fragment read bases (swizzled): global slot for kk,h = 2*kk + h ----
    const int arow = (wr * 128 + l31) * 64;         // + m*2048 + cs + ring
    const int brow = 16384 + (wc * 64 + l31) * 64;  // + n*2048 + cs + ring
    const int cs0 = ((0 + h) ^ pswz) << 4;          // kk = 0
    const int cs1 = ((2 + h) ^ pswz) << 4;          // kk = 1

    int32x16 acc[4][2];
#pragma unroll
    for (int m = 0; m < 4; ++m)
#pragma unroll
        for (int n = 0; n < 2; ++n)
#pragma unroll
            for (int rgi = 0; rgi < 16; ++rgi)
                acc[m][n][rgi] = 0;

    const int NT = K >> 6; // 64 K-tiles

    // prologue: stage K-tiles 0 (ring 0) and 1 (ring 1)
#pragma unroll
    for (int c = 0; c < 4; ++c) stage(0, 0, c);
#pragma unroll
    for (int c = 0; c < 4; ++c) stage(1, 64, c);
    asm volatile("s_waitcnt vmcnt(4)" ::: "memory");
    asm volatile("s_barrier" ::: "memory");

    for (int g = 0; g < NT; ++g) {
        const int rbase = (g & 3) * 32768;
        const int sring = (g + 2) & 3;
        const int skb = (g + 2) << 6;
        const bool do_stage = (g + 2) < NT;
#pragma unroll
        for (int kk = 0; kk < 2; ++kk) {
            const int cs = kk ? cs1 : cs0;

            int32x4 af[4], bf[2];
#pragma unroll
            for (int m = 0; m < 4; ++m)
                af[m] = *(const int32x4*)&lds[rbase + arow + m * 2048 + cs];
#pragma unroll
            for (int n = 0; n < 2; ++n)
                bf[n] = *(const int32x4*)&lds[rbase + brow + n * 2048 + cs];

            if (do_stage) {
                stage(sring, skb, 2 * kk);
                stage(sring, skb, 2 * kk + 1);
            }

            asm volatile("s_barrier" ::: "memory");
            __builtin_amdgcn_s_setprio(1);
#pragma unroll
            for (int m = 0; m < 4; ++m)
#pragma unroll
                for (int n = 0; n < 2; ++n)
                    acc[m][n] = __builtin_amdgcn_mfma_i32_32x32x32_i8(
                        af[m], bf[n], acc[m][n], 0, 0, 0);
            __builtin_amdgcn_s_setprio(0);

            if (kk == 1) {
                if (g < NT - 2)
                    asm volatile("s_waitcnt vmcnt(4)" ::: "memory");
                else
                    asm volatile("s_waitcnt vmcnt(0)" ::: "memory");
            }
            asm volatile("s_barrier" ::: "memory");
        }
    }

    // ---- epilogue: C/D col = lane&31, row = (reg&3)+8*(reg>>2)+4*h ----
    const int col0 = bn * 256 + wc * 64 + l31;       // + n*32
    const int row00 = bm * 256 + wr * 128 + 4 * h;   // + m*32 + (reg&3)+8*(reg>>2)

#pragma unroll
    for (int m = 0; m < 4; ++m) {
        float sv[16];
#pragma unroll
        for (int rgi = 0; rgi < 16; ++rgi)
            sv[rgi] = sa[row00 + m * 32 + (rgi & 3) + 8 * (rgi >> 2)];
#pragma unroll
        for (int n = 0; n < 2; ++n) {
            const int col = col0 + n * 32;
            const float wn = wsc[col];
            const float bb = bias[col];
#pragma unroll
            for (int rgi = 0; rgi < 16; ++rgi) {
                const int row = row00 + m * 32 + (rgi & 3) + 8 * (rgi >> 2);
                out[(size_t)row * N + col] =
                    (float)acc[m][n][rgi] * sv[rgi] * wn + bb;
            }
        }
    }
}

// ---------------------------------------------------------------------------
extern "C" void kernel_launch(void* const* d_in, const int* in_sizes, int n_in,
                              void* d_out, int out_size, void* d_ws, size_t ws_size,
                              hipStream_t stream) {
    const float* inp  = (const float*)d_in[0];
    const int*   w32  = (const int*)d_in[1];   // int8 values carried as int32
    const float* wsc  = (const float*)d_in[2];
    const float* bias = (const float*)d_in[3];
    float* out = (float*)d_out;

    const int N = in_sizes[2];            // 4096
    const int K = in_sizes[1] / N;        // 4096
    const int M = in_sizes[0] / K;        // 8192

    // workspace: q[M*K] i8 | sa[M] f32 | W8[N*K] i8
    int8_t* q  = (int8_t*)d_ws;
    float*  sa = (float*)((char*)d_ws + (size_t)M * K);
    int8_t* w8 = (int8_t*)((char*)d_ws + (size_t)M * K + (size_t)M * 4 + 256);

    const size_t nw4 = ((size_t)N * K) / 4;
    pack_w<<<(int)(nw4 / 256), 256, 0, stream>>>(w32, (uint32_t*)w8);

    quant_rows<<<M, 256, 0, stream>>>(inp, q, sa, K);

    const int nwg = (M / 256) * (N / 256); // 512
    w8a8_gemm<<<nwg, 512, 0, stream>>>(q, w8, sa, wsc, bias, out, M, N, K);
}

// Round 6
// 195.722 us; speedup vs baseline: 1.3801x; 1.0208x over previous
//
#include <hip/hip_runtime.h>
#include <cstdint>

typedef __attribute__((ext_vector_type(4))) int int32x4;
typedef __attribute__((ext_vector_type(16))) int int32x16;

#define GLOBAL_AS __attribute__((address_space(1)))
#define LDS_AS    __attribute__((address_space(3)))

// ---------------------------------------------------------------------------
// Kernel 0: pack int32-carried weight [N*K] (values in [-128,127]) to int8.
// ---------------------------------------------------------------------------
__global__ __launch_bounds__(256) void pack_w(
    const int* __restrict__ w32, uint32_t* __restrict__ w8_as_u32)
{
    const size_t i = (size_t)blockIdx.x * 256 + threadIdx.x; // 4 elems each
    const int4 v = ((const int4*)w32)[i];
    w8_as_u32[i] = (v.x & 0xff) | ((v.y & 0xff) << 8) |
                   ((v.z & 0xff) << 16) | ((uint32_t)(v.w & 0xff) << 24);
}

// ---------------------------------------------------------------------------
// Kernel 1: per-row dynamic symmetric int8 quantization (K=4096).
// ---------------------------------------------------------------------------
__global__ __launch_bounds__(256) void quant_rows(
    const float* __restrict__ in, int8_t* __restrict__ q,
    float* __restrict__ sa, int K)
{
    const int row = blockIdx.x;
    const float4* rp = (const float4*)(in + (size_t)row * K);
    const int t = threadIdx.x;

    float amax = 0.f;
    float4 v[4];
#pragma unroll
    for (int i = 0; i < 4; ++i) {
        v[i] = rp[t + (i << 8)];
        amax = fmaxf(amax,
               fmaxf(fmaxf(fabsf(v[i].x), fabsf(v[i].y)),
                     fmaxf(fabsf(v[i].z), fabsf(v[i].w))));
    }

#pragma unroll
    for (int off = 32; off; off >>= 1)
        amax = fmaxf(amax, __shfl_xor(amax, off));
    __shared__ float smax[4];
    if ((t & 63) == 0) smax[t >> 6] = amax;
    __syncthreads();
    amax = fmaxf(fmaxf(smax[0], smax[1]), fmaxf(smax[2], smax[3]));

    const float scale = (amax > 0.f) ? (amax / 127.f) : 1.f;
    if (t == 0) sa[row] = scale;
    const float rs = 1.f / scale;

    int* qrow = (int*)(q + (size_t)row * K);
#pragma unroll
    for (int i = 0; i < 4; ++i) {
        int a = __float2int_rn(v[i].x * rs);
        int b = __float2int_rn(v[i].y * rs);
        int c = __float2int_rn(v[i].z * rs);
        int d = __float2int_rn(v[i].w * rs);
        a = max(-128, min(127, a));
        b = max(-128, min(127, b));
        c = max(-128, min(127, c));
        d = max(-128, min(127, d));
        qrow[t + (i << 8)] = (a & 0xff) | ((b & 0xff) << 8) |
                             ((c & 0xff) << 16) | ((d & 0xff) << 24);
    }
}

// ---------------------------------------------------------------------------
// Kernel 2 (R6): int8 GEMM, 256x256 tile, FOUR waves each owning 128x128
// (4m x 4n frags of 32x32), mfma_i32_32x32x32_i8, ONE phase / ONE barrier /
// ONE counted vmcnt(8) per K-tile, ring-4 LDS, stage-2-ahead.
//
// Rationale: reads/MFMA drops 0.75 -> 0.5 (16 ds_read_b128 per 32 MFMA per
// wave per K-tile); per-CU LDS ~1280 cyc vs MFMA 1170 cyc -> balanced at the
// matrix-pipe floor. Single barrier per K-tile removes the 4-barrier lockstep.
//
// Ledger (256 threads; chunk = 128 rows x 64 B = 8 KiB = 512 slots; thread t
// covers slots t and t+256): per K-tile stage 4 chunks = 8 gload_lds/thread.
//   prologue: stage tiles 0,1 (16 loads); vmcnt(8) -> tile0 landed; barrier.
//   group g: 8 ds_read (kk=0) | stage 8 for tile g+2 | 8 ds_read (kk=1) |
//            32 MFMA (compiler lgkmcnt) | vmcnt(8) [tail: vmcnt(0)] | barrier.
//   Invariant at end of g: only tile g+2's 8 loads in flight; g+1 landed.
//   WAR: ring slot (g+2)%4 last read in group g-2, 2 barriers back.
//
// Swizzle (unchanged from R5): 16B-slot s of row r holds global slot
// s ^ P(r), P(r) = ((r>>1)^(r>>3))&3; LDS dest linear (rule #21), applied on
// gload_lds GLOBAL source and on ds_read address. All row bases here are
// multiples of 32 -> P(base+l31) = P(l31).
//
// Fragment maps (32x32 i8): A row = lane&31, k = (lane>>5)*16 + byte;
// B col = lane&31, same k. C/D: col = lane&31,
// row = (reg&3) + 8*(reg>>2) + 4*(lane>>5)  [guide-verified, dtype-indep].
// ---------------------------------------------------------------------------
__device__ __forceinline__ void async_load16(const int8_t* g, int8_t* lds) {
    __builtin_amdgcn_global_load_lds((const GLOBAL_AS char*)g,
                                     (LDS_AS char*)lds, 16, 0, 0);
}

__global__ __launch_bounds__(256, 1) void w8a8_gemm(
    const int8_t* __restrict__ Aq, const int8_t* __restrict__ W,
    const float* __restrict__ sa, const float* __restrict__ wsc,
    const float* __restrict__ bias, float* __restrict__ out,
    int M, int N, int K)
{
    __shared__ int8_t lds[4 * 32768]; // 128 KiB -> 1 block/CU

    const int NB = N >> 8; // N/256
    const int nwg = gridDim.x;
    // XCD-aware swizzle (nwg % 8 == 0 -> bijective)
    const int cpx = nwg >> 3;
    const int wg = (blockIdx.x & 7) * cpx + (blockIdx.x >> 3);
    const int bm = wg / NB, bn = wg % NB;

    const int t = threadIdx.x;          // 0..255, 4 waves
    const int lane = t & 63, wid = t >> 6;
    const int wr = wid >> 1, wc = wid & 1;    // 2x2 wave grid, 128x128 each
    const int l31 = lane & 31, h = lane >> 5;
    const int pswz = ((lane >> 1) ^ (lane >> 3)) & 3;

    // ---- staging: thread t covers chunk slots t and t+256 ----
    // slot s: row = s>>2 (thread: t>>2 and t>>2 + 64), swizzled source col
    const int srow = t >> 2;            // 0..63
    const int scol = (((t & 3) ^ ((t >> 3) & 3) ^ ((t >> 5) & 3)) << 4);
    const int8_t* gA = Aq + ((size_t)bm * 256 + srow) * (size_t)K + scol;
    const int8_t* gB = W  + ((size_t)bn * 256 + srow) * (size_t)K + scol;
    const size_t rstep = (size_t)64 * K;   // slot t+256: +64 rows
    const size_t hstep = (size_t)128 * K;  // chunk half: +128 rows
    int8_t* ldsw = &lds[t * 16];

    auto stage = [&](int ring, int kbyte, int c) {
        const int8_t* s0 = (c < 2 ? gA : gB) + (size_t)(c & 1) * hstep + kbyte;
        int8_t* d0 = ldsw + ring * 32768 + (c >> 1) * 16384 + (c & 1) * 8192;
        async_load16(s0, d0);
        async_load16(s0 + rstep, d0 + 4096);
    };

    // ---- fragment read bases (swizzled) ----
    const int aoff = wr * 8192 + l31 * 64;          // + m*2048 + cs + ring
    const int boff = 16384 + wc * 8192 + l31 * 64;  // + n*2048 + cs + ring
    const int cs0 = ((0 + h) ^ pswz) << 4;          // kk = 0
    const int cs1 = ((2 + h) ^ pswz) << 4;          // kk = 1

    int32x16 acc[4][4];
#pragma unroll
    for (int m = 0; m < 4; ++m)
#pragma unroll
        for (int n = 0; n < 4; ++n)
#pragma unroll
            for (int rgi = 0; rgi < 16; ++rgi)
                acc[m][n][rgi] = 0;

    const int NT = K >> 6; // 64 K-tiles

    // prologue: stage K-tiles 0 (ring 0) and 1 (ring 1)
#pragma unroll
    for (int c = 0; c < 4; ++c) stage(0, 0, c);
#pragma unroll
    for (int c = 0; c < 4; ++c) stage(1, 64, c);
    asm volatile("s_waitcnt vmcnt(8)" ::: "memory");
    asm volatile("s_barrier" ::: "memory");

    for (int g = 0; g < NT; ++g) {
        const int rbase = (g & 3) * 32768;
        const int sring = (g + 2) & 3;
        const int skb = (g + 2) << 6;
        const bool do_stage = (g + 2) < NT;

        int32x4 a0[4], b0[4], a1[4], b1[4];
#pragma unroll
        for (int m = 0; m < 4; ++m)
            a0[m] = *(const int32x4*)&lds[rbase + aoff + m * 2048 + cs0];
#pragma unroll
        for (int n = 0; n < 4; ++n)
            b0[n] = *(const int32x4*)&lds[rbase + boff + n * 2048 + cs0];

        if (do_stage) {
#pragma unroll
            for (int c = 0; c < 4; ++c) stage(sring, skb, c);
        }

#pragma unroll
        for (int m = 0; m < 4; ++m)
            a1[m] = *(const int32x4*)&lds[rbase + aoff + m * 2048 + cs1];
#pragma unroll
        for (int n = 0; n < 4; ++n)
            b1[n] = *(const int32x4*)&lds[rbase + boff + n * 2048 + cs1];

#pragma unroll
        for (int m = 0; m < 4; ++m)
#pragma unroll
            for (int n = 0; n < 4; ++n)
                acc[m][n] = __builtin_amdgcn_mfma_i32_32x32x32_i8(
                    a0[m], b0[n], acc[m][n], 0, 0, 0);
#pragma unroll
        for (int m = 0; m < 4; ++m)
#pragma unroll
            for (int n = 0; n < 4; ++n)
                acc[m][n] = __builtin_amdgcn_mfma_i32_32x32x32_i8(
                    a1[m], b1[n], acc[m][n], 0, 0, 0);

        if (g < NT - 2)
            asm volatile("s_waitcnt vmcnt(8)" ::: "memory");
        else
            asm volatile("s_waitcnt vmcnt(0)" ::: "memory");
        asm volatile("s_barrier" ::: "memory");
    }

    // ---- epilogue: C/D col = lane&31, row = (reg&3)+8*(reg>>2)+4*h ----
    const int col0 = bn * 256 + wc * 128 + l31;      // + n*32
    const int row00 = bm * 256 + wr * 128 + 4 * h;   // + m*32 + (reg&3)+8*(reg>>2)

#pragma unroll
    for (int m = 0; m < 4; ++m) {
        float sv[16];
#pragma unroll
        for (int rgi = 0; rgi < 16; ++rgi)
            sv[rgi] = sa[row00 + m * 32 + (rgi & 3) + 8 * (rgi >> 2)];
#pragma unroll
        for (int n = 0; n < 4; ++n) {
            const int col = col0 + n * 32;
            const float wn = wsc[col];
            const float bb = bias[col];
#pragma unroll
            for (int rgi = 0; rgi < 16; ++rgi) {
                const int row = row00 + m * 32 + (rgi & 3) + 8 * (rgi >> 2);
                out[(size_t)row * N + col] =
                    (float)acc[m][n][rgi] * sv[rgi] * wn + bb;
            }
        }
    }
}

// ---------------------------------------------------------------------------
extern "C" void kernel_launch(void* const* d_in, const int* in_sizes, int n_in,
                              void* d_out, int out_size, void* d_ws, size_t ws_size,
                              hipStream_t stream) {
    const float* inp  = (const float*)d_in[0];
    const int*   w32  = (const int*)d_in[1];   // int8 values carried as int32
    const float* wsc  = (const float*)d_in[2];
    const float* bias = (const float*)d_in[3];
    float* out = (float*)d_out;

    const int N = in_sizes[2];            // 4096
    const int K = in_sizes[1] / N;        // 4096
    const int M = in_sizes[0] / K;        // 8192

    // workspace: q[M*K] i8 | sa[M] f32 | W8[N*K] i8
    int8_t* q  = (int8_t*)d_ws;
    float*  sa = (float*)((char*)d_ws + (size_t)M * K);
    int8_t* w8 = (int8_t*)((char*)d_ws + (size_t)M * K + (size_t)M * 4 + 256);

    const size_t nw4 = ((size_t)N * K) / 4;
    pack_w<<<(int)(nw4 / 256), 256, 0, stream>>>(w32, (uint32_t*)w8);

    quant_rows<<<M, 256, 0, stream>>>(inp, q, sa, K);

    const int nwg = (M / 256) * (N / 256); // 512
    w8a8_gemm<<<nwg, 256, 0, stream>>>(q, w8, sa, wsc, bias, out, M, N, K);
}